// Round 5
// baseline (2282.284 us; speedup 1.0000x reference)
//
#include <hip/hip_runtime.h>
#include <stdint.h>
#include <stddef.h>

// ---------------------------------------------------------------------------
// MPSLayer, single-kernel chain, NORMAL launch + software grid barrier.
//
// Round-4 post-mortem: hipLaunchCooperativeKernel with 90KB static LDS was
// rejected by the cooperative occupancy check (64KB sharedMemPerBlock prop)
// -> silent no-op, out stayed zero. Fix: normal <<<128,256>>> launch (grid <=
// CU count => all WGs co-resident by construction; round 2 proved >64KB LDS
// launches fine on the normal path, and we additionally shrink LDS to 39KB
// via a two-phase cross-wave reduction).
// Per-site math / layouts / exchange identical to the PASSING round-3 kernel.
// ---------------------------------------------------------------------------

typedef _Float16 half8   __attribute__((ext_vector_type(8)));
typedef _Float16 half2_t __attribute__((ext_vector_type(2)));
typedef float    floatx4 __attribute__((ext_vector_type(4)));

#define WP_BYTES  66060288u          // 126*128*64*4*8 halfwords * 2B
#define P_ELEMS   524288             // 4 * 2048 * 64 floats (2 MB)
#define BSTRIDE   131072             // 2048*64, one k-quarter partial plane
#define NWG       128

__device__ inline half2_t h2of(half8 v, int j) {
  half2_t r; r[0] = v[2*j]; r[1] = v[2*j+1]; return r;
}
__device__ inline half8 cvt8(floatx4 a, floatx4 b) {
  half8 o;
  o[0]=(_Float16)a[0]; o[1]=(_Float16)a[1]; o[2]=(_Float16)a[2]; o[3]=(_Float16)a[3];
  o[4]=(_Float16)b[0]; o[5]=(_Float16)b[1]; o[6]=(_Float16)b[2]; o[7]=(_Float16)b[3];
  return o;
}
__device__ inline float ld_agent(const float* p) {
  return __hip_atomic_load((float*)p, __ATOMIC_RELAXED, __HIP_MEMORY_SCOPE_AGENT);
}
__device__ inline void st_agent(float* p, float v) {
  __hip_atomic_store(p, v, __ATOMIC_RELAXED, __HIP_MEMORY_SCOPE_AGENT);
}

// --- prep: Wp[s][KT 128][f 64][kg 4][j 8] = W[d=KT>>1][f][e=(KT&1)*32+kg*8+j]
__global__ void prep_wp(const float* __restrict__ wm, _Float16* __restrict__ Wp) {
  const int t  = blockIdx.x * 256 + threadIdx.x;   // 4,128,768 threads
  const int kg = t & 3;
  const int f  = (t >> 2) & 63;
  const int kt = (t >> 8) & 127;
  const int s  = t >> 15;
  const int d  = kt >> 1;
  const int e0 = (kt & 1) * 32 + kg * 8;
  const float* src = wm + ((((size_t)s * 64 + d) * 64 + f) * 64 + e0);
  floatx4 a = *(const floatx4*)src;
  floatx4 b = *(const floatx4*)(src + 4);
  *(half8*)(Wp + (size_t)t * 8) = cvt8(a, b);
}

// --- prep: v0[b][d] = sum_f x[b,0,f] * w0[f,d]  (exact fp32) ----------------
__global__ void prep_v0(const float* __restrict__ x, const float* __restrict__ w0,
                        float* __restrict__ v0) {
  const int b = blockIdx.x * 4 + (threadIdx.x >> 6);
  const int d = threadIdx.x & 63;
  const float* xr = x + (size_t)b * 8192;
  float s = 0.f;
  #pragma unroll
  for (int f = 0; f < 64; ++f) s += xr[f] * w0[f * 64 + d];
  v0[b * 64 + d] = s;
}

// --- grid barrier (generation-based, agent scope; all WGs co-resident) ------
__device__ inline void gridbar(unsigned* cnt, unsigned* gen, unsigned target) {
  __syncthreads();
  if (threadIdx.x == 0) {
    __threadfence();  // release my global stores to device scope
    unsigned prev = __hip_atomic_fetch_add(cnt, 1u, __ATOMIC_ACQ_REL,
                                           __HIP_MEMORY_SCOPE_AGENT);
    if (prev == NWG - 1u) {
      __hip_atomic_store(cnt, 0u, __ATOMIC_RELAXED, __HIP_MEMORY_SCOPE_AGENT);
      __hip_atomic_store(gen, target, __ATOMIC_RELEASE, __HIP_MEMORY_SCOPE_AGENT);
    } else {
      while (__hip_atomic_load(gen, __ATOMIC_ACQUIRE, __HIP_MEMORY_SCOPE_AGENT)
             < target)
        __builtin_amdgcn_s_sleep(8);
    }
  }
  __syncthreads();
}

// --- the whole chain: 128 WGs (32 b-tiles x 4 k-quarters), 256 thr ----------
__global__ __launch_bounds__(256, 1) void mps_chain(
    const _Float16* __restrict__ Wp, const float* __restrict__ x,
    const float* __restrict__ v0, const float* __restrict__ wlast,
    float* __restrict__ part0, float* __restrict__ part1,
    unsigned* __restrict__ bar, float* __restrict__ out)
{
  __shared__ float ub[64 * 17];        // u slice [64 b][16 d]     (4.25 KB)
  __shared__ float red[4 * 32 * 68];   // half-C cross-wave buffer (34 KB)

  const int tid = threadIdx.x;
  const int w = tid >> 6, lane = tid & 63;
  const int c15 = lane & 15, kg = lane >> 4;
  const int kq = (int)blockIdx.x & 3, bt = (int)blockIdx.x >> 2;
  const int b0 = bt * 64;
  unsigned* cnt = bar;
  unsigned* gen = bar + 16;            // 64B apart

  const int ktbase = kq * 32 + w * 8;

  // prefetch site-0 kt=0 B-frags
  half8 pf[4];
  {
    const _Float16* wb0 = Wp + (size_t)ktbase * 2048;
    #pragma unroll
    for (int nt = 0; nt < 4; ++nt)
      pf[nt] = *(const half8*)(wb0 + ((size_t)nt * 16 + c15) * 32 + kg * 8);
  }

  floatx4 C[4][4] = {};
  #pragma unroll 1
  for (int s = 0; s < 126; ++s) {
    const float* up = (s == 0) ? v0 : ((s & 1) ? part0 : part1);
    float* po = (s & 1) ? part1 : part0;

    // u slice: sum k-quarter partial planes of previous site (device scope)
    #pragma unroll
    for (int k = 0; k < 4; ++k) {
      const int li = tid + k * 256;    // 0..1023
      const int bb = li >> 4, dl = li & 15;
      const int gi = (b0 + bb) * 64 + kq * 16 + dl;
      float v;
      if (s == 0) v = ld_agent(up + gi);
      else v = ld_agent(up + gi) + ld_agent(up + BSTRIDE + gi)
             + ld_agent(up + 2 * BSTRIDE + gi) + ld_agent(up + 3 * BSTRIDE + gi);
      ub[bb * 17 + dl] = v;
    }
    __syncthreads();

    // x fragments for this site (fp32 -> fp16), e-halves 0..31 / 32..63
    const int xsite = s + 1;
    half8 xA[4], xB[4];
    #pragma unroll
    for (int mt = 0; mt < 4; ++mt) {
      const float* xp = x + ((size_t)(b0 + mt * 16 + c15) * 128 + xsite) * 64 + kg * 8;
      xA[mt] = cvt8(*(const floatx4*)xp,        *(const floatx4*)(xp + 4));
      xB[mt] = cvt8(*(const floatx4*)(xp + 32), *(const floatx4*)(xp + 36));
    }

    // 8 k-tiles of 32 per wave; d-local = w*4 + (kt>>1)
    const _Float16* wbase = Wp + ((size_t)s * 128 + ktbase) * 2048;
    #pragma unroll
    for (int kt = 0; kt < 8; ++kt) {
      const int dl = w * 4 + (kt >> 1);
      half8 bf[4];
      if (kt == 0) {
        #pragma unroll
        for (int nt = 0; nt < 4; ++nt) bf[nt] = pf[nt];
      } else {
        #pragma unroll
        for (int nt = 0; nt < 4; ++nt)
          bf[nt] = *(const half8*)(wbase + ((size_t)kt * 64 + nt * 16 + c15) * 32 + kg * 8);
      }
      #pragma unroll
      for (int mt = 0; mt < 4; ++mt) {
        const float us = ub[(mt * 16 + c15) * 17 + dl];
        const _Float16 uh = (_Float16)us;
        half2_t uu; uu[0] = uh; uu[1] = uh;
        const half8 xc = (kt & 1) ? xB[mt] : xA[mt];
        half2_t p0 = uu * h2of(xc, 0), p1 = uu * h2of(xc, 1);
        half2_t p2 = uu * h2of(xc, 2), p3 = uu * h2of(xc, 3);
        half8 af;
        af[0]=p0[0]; af[1]=p0[1]; af[2]=p1[0]; af[3]=p1[1];
        af[4]=p2[0]; af[5]=p2[1]; af[6]=p3[0]; af[7]=p3[1];
        #pragma unroll
        for (int nt = 0; nt < 4; ++nt)
          C[mt][nt] = __builtin_amdgcn_mfma_f32_16x16x32_f16(af, bf[nt], C[mt][nt], 0, 0, 0);
      }
    }

    // prefetch next site's kt=0 B-frags (hides L2 latency under the barrier)
    if (s + 1 < 126) {
      const _Float16* wbn = Wp + ((size_t)(s + 1) * 128 + ktbase) * 2048;
      #pragma unroll
      for (int nt = 0; nt < 4; ++nt)
        pf[nt] = *(const half8*)(wbn + ((size_t)nt * 16 + c15) * 32 + kg * 8);
    }

    // cross-wave reduce via LDS in TWO phases (b rows 0..31, then 32..63),
    // then device-scope partial store
    #pragma unroll
    for (int ph = 0; ph < 2; ++ph) {
      #pragma unroll
      for (int m2 = 0; m2 < 2; ++m2) {
        const int mt = ph * 2 + m2;
        #pragma unroll
        for (int nt = 0; nt < 4; ++nt) {
          #pragma unroll
          for (int r = 0; r < 4; ++r)
            red[(w * 32 + m2 * 16 + kg * 4 + r) * 68 + nt * 16 + c15] = C[mt][nt][r];
          C[mt][nt] = (floatx4){0.f, 0.f, 0.f, 0.f};
        }
      }
      __syncthreads();
      #pragma unroll
      for (int k = 0; k < 8; ++k) {
        const int li = tid + k * 256;    // 0..2047
        const int bb = li >> 6, f = li & 63;
        const float sum = red[(0 * 32 + bb) * 68 + f] + red[(1 * 32 + bb) * 68 + f]
                        + red[(2 * 32 + bb) * 68 + f] + red[(3 * 32 + bb) * 68 + f];
        st_agent(po + (size_t)kq * BSTRIDE + (size_t)(b0 + ph * 32 + bb) * 64 + f, sum);
      }
      __syncthreads();
    }

    gridbar(cnt, gen, (unsigned)(s + 1));
  }

  // finalize (site 125 wrote part1): out[b] = sum_d u[b,d] * (wlast[d,:] . x[b,127,:])
  if (kq == 0) {
    for (int bb = w; bb < 64; bb += 4) {
      const int b = b0 + bb;
      const size_t gi = (size_t)b * 64 + lane;
      const float u = ld_agent(part1 + gi) + ld_agent(part1 + BSTRIDE + gi)
                    + ld_agent(part1 + 2 * BSTRIDE + gi) + ld_agent(part1 + 3 * BSTRIDE + gi);
      const float* xr = x + (size_t)b * 8192 + 127 * 64;
      const float* wr = wlast + lane * 64;
      float z = 0.f;
      #pragma unroll
      for (int f = 0; f < 64; f += 4) {
        floatx4 wv = *(const floatx4*)(wr + f);
        floatx4 xv = *(const floatx4*)(xr + f);
        z += wv[0]*xv[0] + wv[1]*xv[1] + wv[2]*xv[2] + wv[3]*xv[3];
      }
      float p = u * z;
      #pragma unroll
      for (int m = 32; m; m >>= 1) p += __shfl_xor(p, m, 64);
      if (lane == 0) out[b] = p;
    }
  }
}

// ---------------------------------------------------------------------------
extern "C" void kernel_launch(void* const* d_in, const int* in_sizes, int n_in,
                              void* d_out, int out_size, void* d_ws, size_t ws_size,
                              hipStream_t stream) {
  const float* x     = (const float*)d_in[0];   // [2048][128][64]
  const float* w0    = (const float*)d_in[1];   // [64][64]
  const float* wmid  = (const float*)d_in[2];   // [126][64][64][64]
  const float* wlast = (const float*)d_in[3];   // [64][64]
  float* out = (float*)d_out;                   // [2048]

  _Float16* Wp  = (_Float16*)d_ws;
  float* part0  = (float*)((char*)d_ws + WP_BYTES);
  float* part1  = part0 + P_ELEMS;
  float* v0     = part1 + P_ELEMS;
  unsigned* bar = (unsigned*)(v0 + 131072);
  // ws use: 66.06 MB + 2*2 MB + 0.5 MB + 256 B

  prep_wp<<<16128, 256, 0, stream>>>(wmid, Wp);
  prep_v0<<<512,   256, 0, stream>>>(x, w0, v0);
  hipMemsetAsync(bar, 0, 256, stream);

  mps_chain<<<NWG, 256, 0, stream>>>(Wp, x, v0, wlast, part0, part1, bar, out);
}